// Round 10
// baseline (394.508 us; speedup 1.0000x reference)
//
#include <hip/hip_runtime.h>
#include <hip/hip_bf16.h>

// DenoisingPotential: x_{t+1} = x_t + alpha * grad_phi(x_t), 10 iters.
// grad = (pacc - sum_k w_k y_k)/l,  y_k = P_k x,  w_k = exp(e_k + Pmu_k.x - 0.5 x.y_k)
//
// R13: R12's 2-deep pipeline was correct but spilled ~20MB (yA/yB live set
// 180 regs > the 128-VGPR pin; spilled y => HBM round-trip inside the chain,
// cancelling the pipeline gain). Every round reports exactly VGPR=128; with
// launch_bounds(256,2) the allocator pins at 128 + spills rather than use the
// 256 budget. Occupancy is LDS-bound at 2 blocks/CU anyway, so grant the
// allocator headroom: SINGLE CHANGE vs R12 -> __launch_bounds__(256,1).
// Expect VGPR ~160-240, no spill (WRITE back to 16.4MB), same occupancy,
// pipeline finally effective.

typedef __attribute__((ext_vector_type(4))) float f32x4;
typedef __attribute__((ext_vector_type(8))) short bf16x8;  // 8 bf16 = 4 VGPRs

#define KC 32
#define NITER 10
#define XROW 72        // bf16 elems per point-row in xs staging (pad vs 64)
#define WT_PITCH 40    // bf16 pitch of weight stash (pad vs 32)
#define PW_BYTES 7168  // per-wave: xsw(4608, aliased by pmxw 4096) + wtw(2560)
#define PSTG 8192      // one k's P fragments (64x64 bf16)
#define NBUF 4         // staging buffers; distance-3 stage, 32%4==0 clean wrap
// LDS total: 4*7168 + 4*8192 = 61440 B -> 2 blocks/CU

static __device__ __forceinline__ unsigned pk_bf16(float a, float b) {
  __hip_bfloat16 ha = __float2bfloat16(a), hb = __float2bfloat16(b);
  unsigned short ua = *(unsigned short*)&ha, ub = *(unsigned short*)&hb;
  return (unsigned)ua | ((unsigned)ub << 16);
}

// butterfly sum with lane^16: permlane16_swap is pure VALU (sum of the two
// outputs = x[l] + x[l^16] in every lane)
static __device__ __forceinline__ float red16(float x) {
#if __has_builtin(__builtin_amdgcn_permlane16_swap)
  int xi = __float_as_int(x);
  auto pr = __builtin_amdgcn_permlane16_swap(xi, xi, false, false);
  return __int_as_float(pr[0]) + __int_as_float(pr[1]);
#else
  int v = __builtin_amdgcn_ds_swizzle(__float_as_int(x), 0x401F);
  return x + __int_as_float(v);
#endif
}
// butterfly sum with lane^32 (VALU permlane32_swap)
static __device__ __forceinline__ float red32(float x) {
  int xi = __float_as_int(x);
  auto pr = __builtin_amdgcn_permlane32_swap(xi, xi, false, false);
  return __int_as_float(pr[0]) + __int_as_float(pr[1]);
}

// async global->LDS, 16B per lane; ldst is wave-uniform base (HW adds lane*16),
// gsrc is the per-lane source address.
static __device__ __forceinline__ void stage16(const void* gsrc, void* ldst) {
  __builtin_amdgcn_global_load_lds(
      (const __attribute__((address_space(1))) unsigned int*)gsrc,
      (__attribute__((address_space(3))) unsigned int*)ldst, 16, 0, 0);
}

// ---------------- precompute 1: per-k P = A^T A, Pmu, e, swizzled P ----------
__global__ void precompute1(const float* __restrict__ A, const float* __restrict__ mu,
                            const float* __restrict__ c,
                            float* __restrict__ Pmu_g, float* __restrict__ e_g,
                            __hip_bfloat16* __restrict__ Psw) {
  __shared__ float As[64 * 64];
  __shared__ float Pk[64 * 64];
  const int k = blockIdx.x, tid = threadIdx.x;
  const float* Ak = A + k * 4096;
  for (int idx = tid; idx < 1024; idx += 256)
    *(f32x4*)&As[idx * 4] = *(const f32x4*)&Ak[idx * 4];
  __syncthreads();

  // thread -> row i = tid>>2, col strip lg*16..lg*16+15
  const int i = tid >> 2, lg = tid & 3;
  float acc[16] = {};
  for (int j = 0; j < 64; ++j) {
    float ai = As[j * 64 + i];  // broadcast within quad
    const f32x4* row = (const f32x4*)&As[j * 64 + lg * 16];  // broadcast across i
#pragma unroll
    for (int g = 0; g < 4; ++g) {
      f32x4 v = row[g];
#pragma unroll
      for (int r = 0; r < 4; ++r) acc[g * 4 + r] += ai * v[r];
    }
  }
#pragma unroll
  for (int g = 0; g < 4; ++g)
#pragma unroll
    for (int r = 0; r < 4; ++r) Pk[i * 64 + lg * 16 + g * 4 + r] = acc[g * 4 + r];
  __syncthreads();

  if (tid < 64) {
    // Pmu[i] = sum_l P[l][i]*mu[l]  (P symmetric; transposed read = stride-1)
    float s = 0.f;
    for (int l = 0; l < 64; ++l) s += Pk[l * 64 + tid] * mu[k * 64 + l];
    Pmu_g[k * 64 + tid] = s;
    float v = mu[k * 64 + tid] * s;
#pragma unroll
    for (int off = 1; off < 64; off <<= 1) v += __shfl_xor(v, off, 64);
    if (tid == 0) e_g[k] = c[k] - 0.5f * v;
  }

  // A-frag order for the main GEMM: flat idx = f*512 + lane*8 + j,
  // f=(mt,s): val = P[dim_in = s*32 + qq*8 + j][dim_out = mt*16 + l4]
  unsigned* Psw32 = (unsigned*)(Psw + k * 4096);
  for (int idx2 = tid; idx2 < 2048; idx2 += 256) {
    int idx = idx2 << 1;  // even j
    int f = idx >> 9, ln = (idx >> 3) & 63, j = idx & 7;
    int mt = f >> 1, s = f & 1, qq = ln >> 4, l4 = ln & 15;
    int col = mt * 16 + l4, rb = s * 32 + qq * 8 + j;
    Psw32[idx2] = pk_bf16(Pk[rb * 64 + col], Pk[(rb + 1) * 64 + col]);
  }
}

// ---------------- precompute 2: Pmu fragment swizzles -----------------------
__global__ void precompute2(const float* __restrict__ Pmu_g,
                            __hip_bfloat16* __restrict__ PmuA,
                            __hip_bfloat16* __restrict__ PmuB) {
  const int tid = threadIdx.x;
  // PmuA (pmx GEMM A-operand): A[m=cluster][kk=dim]; frag f=(mtc,s)
  for (int idx = tid; idx < 2048; idx += 256) {
    int f = idx >> 9, lane = (idx >> 3) & 63, j = idx & 7;
    int mtc = f >> 1, s = f & 1, qq = lane >> 4, l4 = lane & 15;
    PmuA[idx] = __float2bfloat16(Pmu_g[(mtc * 16 + l4) * 64 + s * 32 + qq * 8 + j]);
  }
  // PmuB (pacc GEMM A-operand): A[m=dim][kk=cluster]; frag f=mtd (K=32, 1 step)
  for (int idx = tid; idx < 2048; idx += 256) {
    int f = idx >> 9, lane = (idx >> 3) & 63, j = idx & 7;
    int qq = lane >> 4, l4 = lane & 15;
    PmuB[idx] = __float2bfloat16(Pmu_g[(qq * 8 + j) * 64 + f * 16 + l4]);
  }
}

// ---------------- main kernel ----------------------------------------------
// 256 thr (4 waves), 32 pts/wave, grid 512 (2 blocks/CU, LDS-capped). P staged
// per k into 4 LDS buffers (wave w stages frags 2w,2w+1), stage distance 3,
// counted vmcnt(2) + raw s_barrier per k-step, 2-deep y pipeline (yA/yB).
__launch_bounds__(256, 1)
__global__ void denoise_main(const float* __restrict__ x_in,
                             const float* __restrict__ e_g,
                             const float* __restrict__ alpha_g,
                             const __hip_bfloat16* __restrict__ Psw,
                             const __hip_bfloat16* __restrict__ PmuA,
                             const __hip_bfloat16* __restrict__ PmuB,
                             float* __restrict__ out) {
  __shared__ __attribute__((aligned(16))) char scratch[4 * PW_BYTES + NBUF * PSTG];  // 60 KB

  const int tid = threadIdx.x;
  const int wave = tid >> 6, lane = tid & 63;
  const int q = lane >> 4, l4 = lane & 15;
  const int base_pt = blockIdx.x * 128 + wave * 32;
  const float alpha = alpha_g[0];

  char* pw = scratch + wave * PW_BYTES;
  __hip_bfloat16* xsw = (__hip_bfloat16*)pw;           // [32][XROW] bf16 staging
  float* pmxw = (float*)pw;                            // [32][32] f32 (xsw dead)
  __hip_bfloat16* wtw = (__hip_bfloat16*)(pw + 4608);  // [32][WT_PITCH] bf16
  char* pstg = scratch + 4 * PW_BYTES;                 // [NBUF][PSTG] stage bufs

  const char* PswB = (const char*)Psw;        // k block = 8192 B, frag f = 1024 B
  const bf16x8* PmuAF = (const bf16x8*)PmuA;  // frag idx = f*64 + lane
  const bf16x8* PmuBF = (const bf16x8*)PmuB;

  const f32x4 Z4 = {0.f, 0.f, 0.f, 0.f};
  const int f0 = 2 * wave, f1 = 2 * wave + 1;  // this wave's staging fragments

  // ---- initial staging: k=0,1,2 (6 loads; drained by compiler's xm waits) --
  stage16(PswB + 0 * PSTG + f0 * 1024 + lane * 16, pstg + 0 * PSTG + f0 * 1024);
  stage16(PswB + 0 * PSTG + f1 * 1024 + lane * 16, pstg + 0 * PSTG + f1 * 1024);
  stage16(PswB + 1 * PSTG + f0 * 1024 + lane * 16, pstg + 1 * PSTG + f0 * 1024);
  stage16(PswB + 1 * PSTG + f1 * 1024 + lane * 16, pstg + 1 * PSTG + f1 * 1024);
  stage16(PswB + 2 * PSTG + f0 * 1024 + lane * 16, pstg + 2 * PSTG + f0 * 1024);
  stage16(PswB + 2 * PSTG + f1 * 1024 + lane * 16, pstg + 2 * PSTG + f1 * 1024);

  // x master, C-layout: xm[mt][nt][r] = x[dim = mt*16+q*4+r][pt = nt*16+l4]
  f32x4 xm[4][2];
#pragma unroll
  for (int mt = 0; mt < 4; ++mt)
#pragma unroll
    for (int nt = 0; nt < 2; ++nt)
      xm[mt][nt] = *(const f32x4*)&x_in[(base_pt + nt * 16 + l4) * 64 + mt * 16 + q * 4];

  // e for pmx spill: cluster row mtc*16 + q*4 + r  ->  ev[mtc][r]
  f32x4 ev[2];
#pragma unroll
  for (int mtc = 0; mtc < 2; ++mtc) ev[mtc] = *(const f32x4*)&e_g[mtc * 16 + q * 4];

  // pipeline state (static names per rule #20)
  f32x4 yA[4][2], yB[4][2];
  f32x4 accY[4][2];
  float lsum0, lsum1;
  bf16x8 bx[2][2];

  // MFMA block reading P frags for one k straight from a staged LDS buffer;
  // s-outer emission (R9): 8 independent s=0 MFMAs, then the 8 s=1 MFMAs.
  auto mfma_from = [&](f32x4(&y)[4][2], const char* pc) {
    bf16x8 apr[4][2];
#pragma unroll
    for (int mt = 0; mt < 4; ++mt)
#pragma unroll
      for (int s = 0; s < 2; ++s)
        apr[mt][s] = *(const bf16x8*)(pc + (mt * 2 + s) * 1024 + lane * 16);
#pragma unroll
    for (int mt = 0; mt < 4; ++mt)
#pragma unroll
      for (int nt = 0; nt < 2; ++nt)
        y[mt][nt] = __builtin_amdgcn_mfma_f32_16x16x32_bf16(apr[mt][0], bx[0][nt], Z4, 0, 0, 0);
#pragma unroll
    for (int mt = 0; mt < 4; ++mt)
#pragma unroll
      for (int nt = 0; nt < 2; ++nt)
        y[mt][nt] = __builtin_amdgcn_mfma_f32_16x16x32_bf16(apr[mt][1], bx[1][nt], y[mt][nt], 0, 0, 0);
  };

  // softmax chain for one k (pk reads hoisted first: ds latency hides in dot)
  auto chain = [&](const f32x4(&y)[4][2], int k) {
    const float pk0 = pmxw[k * 32 + l4];  // includes e_k
    const float pk1 = pmxw[k * 32 + 16 + l4];
    f32x4 d0 = xm[0][0] * y[0][0];
    f32x4 d1 = xm[0][1] * y[0][1];
#pragma unroll
    for (int mt = 1; mt < 4; ++mt) {
      d0 += xm[mt][0] * y[mt][0];
      d1 += xm[mt][1] * y[mt][1];
    }
    float xy0 = (d0[0] + d0[1]) + (d0[2] + d0[3]);
    float xy1 = (d1[0] + d1[1]) + (d1[2] + d1[3]);
    xy0 = red32(red16(xy0));
    xy1 = red32(red16(xy1));
    const float w0 = __expf(pk0 - 0.5f * xy0);
    const float w1 = __expf(pk1 - 0.5f * xy1);
    lsum0 += w0;
    lsum1 += w1;
    if (q == 0) {
      wtw[l4 * WT_PITCH + k] = __float2bfloat16(w0);
      wtw[(16 + l4) * WT_PITCH + k] = __float2bfloat16(w1);
    }
#pragma unroll
    for (int mt = 0; mt < 4; ++mt) {
      accY[mt][0] += w0 * y[mt][0];
      accY[mt][1] += w1 * y[mt][1];
    }
  };

  // issue this wave's staging of k-index ks into buf[ks&3]
  auto stage_next = [&](int k) {
    const int ks = (k + 3) & (KC - 1);  // steps 29/30/31 pre-stage next iter
    const char* ps = PswB + ks * PSTG;
    char* pd = pstg + (ks & (NBUF - 1)) * PSTG;
    stage16(ps + f0 * 1024 + lane * 16, pd + f0 * 1024);
    stage16(ps + f1 * 1024 + lane * 16, pd + f1 * 1024);
  };
  auto syncstep = [&]() {
    // own oldest stage done (newest 2 loads may fly); publish to block. NO drain.
    asm volatile("s_waitcnt vmcnt(2)" ::: "memory");
    __builtin_amdgcn_s_barrier();
    asm volatile("" ::: "memory");
  };

#pragma unroll 1
  for (int it = 0; it < NITER; ++it) {
    // ---- stage x (bf16) into wave-private rows [pt][dim], XROW-padded ----
#pragma unroll
    for (int mt = 0; mt < 4; ++mt)
#pragma unroll
      for (int nt = 0; nt < 2; ++nt) {
        uint2 v;
        v.x = pk_bf16(xm[mt][nt][0], xm[mt][nt][1]);
        v.y = pk_bf16(xm[mt][nt][2], xm[mt][nt][3]);
        *(uint2*)&xsw[(nt * 16 + l4) * XROW + mt * 16 + q * 4] = v;
      }

    // ---- B-frags of x: B[kk=dim=s*32+q*8+j][n=pt=l4] (constant over k) ----
#pragma unroll
    for (int s = 0; s < 2; ++s)
#pragma unroll
      for (int nt = 0; nt < 2; ++nt)
        bx[s][nt] = *(const bf16x8*)&xsw[(nt * 16 + l4) * XROW + s * 32 + q * 8];

    // ---- pmx GEMM (s-outer) ----
    f32x4 pmx[2][2];
#pragma unroll
    for (int mtc = 0; mtc < 2; ++mtc)
#pragma unroll
      for (int nt = 0; nt < 2; ++nt)
        pmx[mtc][nt] =
            __builtin_amdgcn_mfma_f32_16x16x32_bf16(PmuAF[(mtc * 2) * 64 + lane], bx[0][nt], Z4, 0, 0, 0);
#pragma unroll
    for (int mtc = 0; mtc < 2; ++mtc)
#pragma unroll
      for (int nt = 0; nt < 2; ++nt)
        pmx[mtc][nt] = __builtin_amdgcn_mfma_f32_16x16x32_bf16(PmuAF[(mtc * 2 + 1) * 64 + lane],
                                                               bx[1][nt], pmx[mtc][nt], 0, 0, 0);
    // spill pmx + e (folded) to wave-private LDS [cluster32][pt32] f32
#pragma unroll
    for (int mtc = 0; mtc < 2; ++mtc)
#pragma unroll
      for (int nt = 0; nt < 2; ++nt)
#pragma unroll
        for (int r = 0; r < 4; ++r)
          pmxw[(mtc * 16 + q * 4 + r) * 32 + nt * 16 + l4] = pmx[mtc][nt][r] + ev[mtc][r];

#pragma unroll
    for (int mt = 0; mt < 4; ++mt)
#pragma unroll
      for (int nt = 0; nt < 2; ++nt) accY[mt][nt] = Z4;
    lsum0 = 0.f;
    lsum1 = 0.f;

    // invariant entering the k-loop: buf0,buf1 staged & published, buf2 may
    // fly (it=0: initial stages drained by compiler waits; it>0: seam stages
    // from steps 29-31, published by their barriers)
    syncstep();

    // ---- 2-deep pipelined k-loop: MFMA(k+1) issues before chain(k) --------
    mfma_from(yA, pstg + 0 * PSTG);  // prime: y_0
#pragma unroll 1
    for (int kp = 0; kp < 15; ++kp) {
      const int kA = 2 * kp, kB = 2 * kp + 1;
      stage_next(kA);
      mfma_from(yB, pstg + ((kA + 1) & (NBUF - 1)) * PSTG);  // y_{kA+1}
      chain(yA, kA);
      syncstep();
      stage_next(kB);
      mfma_from(yA, pstg + ((kB + 1) & (NBUF - 1)) * PSTG);  // y_{kB+1}
      chain(yB, kB);
      syncstep();
    }
    // k=30: last MFMA prefetch (y_31); k=31: drain
    stage_next(30);
    mfma_from(yB, pstg + (31 & (NBUF - 1)) * PSTG);  // y_31
    chain(yA, 30);
    syncstep();
    stage_next(31);
    chain(yB, 31);
    syncstep();

    // ---- pacc[dim][pt] = sum_k Pmu[k][dim] * wt[k][pt]  (one K=32 GEMM) ----
    bf16x8 wtf[2];
#pragma unroll
    for (int nt = 0; nt < 2; ++nt)
      wtf[nt] = *(const bf16x8*)&wtw[(nt * 16 + l4) * WT_PITCH + q * 8];
    f32x4 pacc[4][2];
#pragma unroll
    for (int mt = 0; mt < 4; ++mt) {
      bf16x8 a = PmuBF[mt * 64 + lane];
      pacc[mt][0] = __builtin_amdgcn_mfma_f32_16x16x32_bf16(a, wtf[0], Z4, 0, 0, 0);
      pacc[mt][1] = __builtin_amdgcn_mfma_f32_16x16x32_bf16(a, wtf[1], Z4, 0, 0, 0);
    }

    // ---- x += (alpha/l) * (pacc - accY) ----
    const float c0 = alpha / lsum0;
    const float c1 = alpha / lsum1;
#pragma unroll
    for (int mt = 0; mt < 4; ++mt) {
      xm[mt][0] += c0 * (pacc[mt][0] - accY[mt][0]);
      xm[mt][1] += c1 * (pacc[mt][1] - accY[mt][1]);
    }
  }  // iterations

  // ---- direct f32x4 stores: 64B-contiguous per quad-row, fully in-bounds ---
#pragma unroll
  for (int mt = 0; mt < 4; ++mt)
#pragma unroll
    for (int nt = 0; nt < 2; ++nt)
      *(f32x4*)&out[(base_pt + nt * 16 + l4) * 64 + mt * 16 + q * 4] = xm[mt][nt];
}

extern "C" void kernel_launch(void* const* d_in, const int* in_sizes, int n_in,
                              void* d_out, int out_size, void* d_ws, size_t ws_size,
                              hipStream_t stream) {
  (void)in_sizes; (void)n_in; (void)out_size; (void)ws_size;
  const float* x = (const float*)d_in[0];
  const float* c = (const float*)d_in[1];
  const float* mu = (const float*)d_in[2];
  const float* A = (const float*)d_in[3];
  const float* alpha = (const float*)d_in[4];
  float* out = (float*)d_out;

  char* ws = (char*)d_ws;
  float* Pmu_g = (float*)(ws);                           // 8192 B
  float* e_g = (float*)(ws + 8192);                      // 128 B (pad to 256)
  __hip_bfloat16* PmuA = (__hip_bfloat16*)(ws + 8448);   // 4096 B
  __hip_bfloat16* PmuB = (__hip_bfloat16*)(ws + 12544);  // 4096 B
  __hip_bfloat16* Psw = (__hip_bfloat16*)(ws + 16640);   // 262144 B

  precompute1<<<32, 256, 0, stream>>>(A, mu, c, Pmu_g, e_g, Psw);
  precompute2<<<1, 256, 0, stream>>>(Pmu_g, PmuA, PmuB);
  denoise_main<<<512, 256, 0, stream>>>(x, e_g, alpha, Psw, PmuA, PmuB, out);
}

// Round 11
// 286.945 us; speedup vs baseline: 1.3749x; 1.3749x over previous
//
#include <hip/hip_runtime.h>
#include <hip/hip_bf16.h>

// DenoisingPotential: x_{t+1} = x_t + alpha * grad_phi(x_t), 10 iters.
// grad = (pacc - sum_k w_k y_k)/l,  y_k = P_k x,  w_k = exp(e_k + Pmu_k.x - 0.5 x.y_k)
//
// R14: structural race is over -- R10/R12/R13 proved 2-deep pipelining either
// spills (128-VGPR pin) or halves occupancy (unpinned, 152 VGPR -> 1 blk/CU,
// 344us). R9 (233us, 737 TF = 30% of dense peak) is the base. Two proven
// cheap levers applied:
//  (1) T5 s_setprio(1) around the MFMA cluster -- R9's regime (independent
//      waves, no barriers, MFMA/VALU alternation) is where it measured +4-7%.
//  (2) precompute2 eliminated: PmuA/PmuB fragments staged into block LDS in
//      the denoise prologue from Pmu_g (one barrier before the iter loop;
//      k-loop stays barrier-free). Kills one launch + the 1-block serial
//      kernel + per-iteration global frag loads (now ds_read_b128).

typedef __attribute__((ext_vector_type(4))) float f32x4;
typedef __attribute__((ext_vector_type(8))) short bf16x8;  // 8 bf16 = 4 VGPRs

#define KC 32
#define NITER 10
#define XROW 72        // bf16 elems per point-row in xs staging (pad vs 64)
#define WT_PITCH 40    // bf16 pitch of weight stash (pad vs 32)
#define PW_BYTES 7168  // per-wave: xsw(4608, aliased by pmxw 4096) + wtw(2560)
// LDS total: 4*7168 + 2*4096 (PmuA/PmuB bf16) = 36864 B

static __device__ __forceinline__ unsigned pk_bf16(float a, float b) {
  __hip_bfloat16 ha = __float2bfloat16(a), hb = __float2bfloat16(b);
  unsigned short ua = *(unsigned short*)&ha, ub = *(unsigned short*)&hb;
  return (unsigned)ua | ((unsigned)ub << 16);
}

// butterfly sum with lane^16: permlane16_swap is pure VALU (sum of the two
// outputs = x[l] + x[l^16] in every lane)
static __device__ __forceinline__ float red16(float x) {
#if __has_builtin(__builtin_amdgcn_permlane16_swap)
  int xi = __float_as_int(x);
  auto pr = __builtin_amdgcn_permlane16_swap(xi, xi, false, false);
  return __int_as_float(pr[0]) + __int_as_float(pr[1]);
#else
  int v = __builtin_amdgcn_ds_swizzle(__float_as_int(x), 0x401F);
  return x + __int_as_float(v);
#endif
}
// butterfly sum with lane^32 (VALU permlane32_swap)
static __device__ __forceinline__ float red32(float x) {
  int xi = __float_as_int(x);
  auto pr = __builtin_amdgcn_permlane32_swap(xi, xi, false, false);
  return __int_as_float(pr[0]) + __int_as_float(pr[1]);
}

// ---------------- precompute 1: per-k P = A^T A, Pmu, e, swizzled P ----------
__global__ void precompute1(const float* __restrict__ A, const float* __restrict__ mu,
                            const float* __restrict__ c,
                            float* __restrict__ Pmu_g, float* __restrict__ e_g,
                            __hip_bfloat16* __restrict__ Psw) {
  __shared__ float As[64 * 64];
  __shared__ float Pk[64 * 64];
  const int k = blockIdx.x, tid = threadIdx.x;
  const float* Ak = A + k * 4096;
  for (int idx = tid; idx < 1024; idx += 256)
    *(f32x4*)&As[idx * 4] = *(const f32x4*)&Ak[idx * 4];
  __syncthreads();

  // thread -> row i = tid>>2, col strip lg*16..lg*16+15
  const int i = tid >> 2, lg = tid & 3;
  float acc[16] = {};
  for (int j = 0; j < 64; ++j) {
    float ai = As[j * 64 + i];  // broadcast within quad
    const f32x4* row = (const f32x4*)&As[j * 64 + lg * 16];  // broadcast across i
#pragma unroll
    for (int g = 0; g < 4; ++g) {
      f32x4 v = row[g];
#pragma unroll
      for (int r = 0; r < 4; ++r) acc[g * 4 + r] += ai * v[r];
    }
  }
#pragma unroll
  for (int g = 0; g < 4; ++g)
#pragma unroll
    for (int r = 0; r < 4; ++r) Pk[i * 64 + lg * 16 + g * 4 + r] = acc[g * 4 + r];
  __syncthreads();

  if (tid < 64) {
    // Pmu[i] = sum_l P[l][i]*mu[l]  (P symmetric; transposed read = stride-1)
    float s = 0.f;
    for (int l = 0; l < 64; ++l) s += Pk[l * 64 + tid] * mu[k * 64 + l];
    Pmu_g[k * 64 + tid] = s;
    float v = mu[k * 64 + tid] * s;
#pragma unroll
    for (int off = 1; off < 64; off <<= 1) v += __shfl_xor(v, off, 64);
    if (tid == 0) e_g[k] = c[k] - 0.5f * v;
  }

  // A-frag order for the main GEMM: flat idx = f*512 + lane*8 + j,
  // f=(mt,s): val = P[dim_in = s*32 + qq*8 + j][dim_out = mt*16 + l4]
  unsigned* Psw32 = (unsigned*)(Psw + k * 4096);
  for (int idx2 = tid; idx2 < 2048; idx2 += 256) {
    int idx = idx2 << 1;  // even j
    int f = idx >> 9, ln = (idx >> 3) & 63, j = idx & 7;
    int mt = f >> 1, s = f & 1, qq = ln >> 4, l4 = ln & 15;
    int col = mt * 16 + l4, rb = s * 32 + qq * 8 + j;
    Psw32[idx2] = pk_bf16(Pk[rb * 64 + col], Pk[(rb + 1) * 64 + col]);
  }
}

// ---------------- main kernel ----------------------------------------------
// 256 thr (4 waves), 32 pts/wave, grid 512. k-loop barrier-free; all per-wave
// LDS is wave-private. P via register double-buffer from L2. Pmu fragments
// staged into block LDS once in the prologue (one barrier, before iter loop).
__launch_bounds__(256, 2)
__global__ void denoise_main(const float* __restrict__ x_in,
                             const float* __restrict__ e_g,
                             const float* __restrict__ alpha_g,
                             const __hip_bfloat16* __restrict__ Psw,
                             const float* __restrict__ Pmu_g,
                             float* __restrict__ out) {
  __shared__ __attribute__((aligned(16))) char scratch[4 * PW_BYTES];  // 28 KB
  __shared__ __attribute__((aligned(16))) __hip_bfloat16 pmuA_s[2048];  // 4 KB
  __shared__ __attribute__((aligned(16))) __hip_bfloat16 pmuB_s[2048];  // 4 KB

  const int tid = threadIdx.x;
  const int wave = tid >> 6, lane = tid & 63;
  const int q = lane >> 4, l4 = lane & 15;
  const int base_pt = blockIdx.x * 128 + wave * 32;
  const float alpha = alpha_g[0];

  char* pw = scratch + wave * PW_BYTES;
  __hip_bfloat16* xsw = (__hip_bfloat16*)pw;           // [32][XROW] bf16 staging
  float* pmxw = (float*)pw;                            // [32][32] f32 (xsw dead)
  __hip_bfloat16* wtw = (__hip_bfloat16*)(pw + 4608);  // [32][WT_PITCH] bf16

  const bf16x8* PswF = (const bf16x8*)Psw;  // frag idx = k*512 + f*64 + lane

  // ---- prologue: stage PmuA/PmuB fragment layouts into LDS (from Pmu_g) ----
  // PmuA (pmx GEMM A-operand): A[m=cluster][kk=dim]; frag f=(mtc,s)
  for (int idx = tid; idx < 2048; idx += 256) {
    int f = idx >> 9, ln = (idx >> 3) & 63, j = idx & 7;
    int mtc = f >> 1, s = f & 1, qq = ln >> 4, l4i = ln & 15;
    pmuA_s[idx] = __float2bfloat16(Pmu_g[(mtc * 16 + l4i) * 64 + s * 32 + qq * 8 + j]);
  }
  // PmuB (pacc GEMM A-operand): A[m=dim][kk=cluster]; frag f=mtd (K=32, 1 step)
  for (int idx = tid; idx < 2048; idx += 256) {
    int f = idx >> 9, ln = (idx >> 3) & 63, j = idx & 7;
    int qq = ln >> 4, l4i = ln & 15;
    pmuB_s[idx] = __float2bfloat16(Pmu_g[(qq * 8 + j) * 64 + f * 16 + l4i]);
  }

  // x master, C-layout: xm[mt][nt][r] = x[dim = mt*16+q*4+r][pt = nt*16+l4]
  f32x4 xm[4][2];
#pragma unroll
  for (int mt = 0; mt < 4; ++mt)
#pragma unroll
    for (int nt = 0; nt < 2; ++nt)
      xm[mt][nt] = *(const f32x4*)&x_in[(base_pt + nt * 16 + l4) * 64 + mt * 16 + q * 4];

  // e for pmx spill: cluster row mtc*16 + q*4 + r  ->  ev[mtc][r]
  f32x4 ev[2];
#pragma unroll
  for (int mtc = 0; mtc < 2; ++mtc) ev[mtc] = *(const f32x4*)&e_g[mtc * 16 + q * 4];

  const f32x4 Z4 = {0.f, 0.f, 0.f, 0.f};
  const bf16x8* PmuAF = (const bf16x8*)pmuA_s;  // frag idx = f*64 + lane
  const bf16x8* PmuBF = (const bf16x8*)pmuB_s;

  __syncthreads();  // Pmu fragments staged; k-loop below stays barrier-free

#pragma unroll 1
  for (int it = 0; it < NITER; ++it) {
    // ---- stage x (bf16) into wave-private rows [pt][dim], XROW-padded ----
#pragma unroll
    for (int mt = 0; mt < 4; ++mt)
#pragma unroll
      for (int nt = 0; nt < 2; ++nt) {
        uint2 v;
        v.x = pk_bf16(xm[mt][nt][0], xm[mt][nt][1]);
        v.y = pk_bf16(xm[mt][nt][2], xm[mt][nt][3]);
        *(uint2*)&xsw[(nt * 16 + l4) * XROW + mt * 16 + q * 4] = v;
      }

    // ---- B-frags of x: B[kk=dim=s*32+q*8+j][n=pt=l4] (constant over k) ----
    bf16x8 bx[2][2];
#pragma unroll
    for (int s = 0; s < 2; ++s)
#pragma unroll
      for (int nt = 0; nt < 2; ++nt)
        bx[s][nt] = *(const bf16x8*)&xsw[(nt * 16 + l4) * XROW + s * 32 + q * 8];

    // ---- preload P(k=0) fragments into register buffer 0 ----
    bf16x8 ap[2][4][2];
#pragma unroll
    for (int mt = 0; mt < 4; ++mt)
#pragma unroll
      for (int s = 0; s < 2; ++s)
        ap[0][mt][s] = PswF[(mt * 2 + s) * 64 + lane];

    // ---- pmx GEMM (s-outer; Pmu frags from LDS) ----
    f32x4 pmx[2][2];
    __builtin_amdgcn_s_setprio(1);
#pragma unroll
    for (int mtc = 0; mtc < 2; ++mtc)
#pragma unroll
      for (int nt = 0; nt < 2; ++nt)
        pmx[mtc][nt] =
            __builtin_amdgcn_mfma_f32_16x16x32_bf16(PmuAF[(mtc * 2) * 64 + lane], bx[0][nt], Z4, 0, 0, 0);
#pragma unroll
    for (int mtc = 0; mtc < 2; ++mtc)
#pragma unroll
      for (int nt = 0; nt < 2; ++nt)
        pmx[mtc][nt] = __builtin_amdgcn_mfma_f32_16x16x32_bf16(PmuAF[(mtc * 2 + 1) * 64 + lane],
                                                               bx[1][nt], pmx[mtc][nt], 0, 0, 0);
    __builtin_amdgcn_s_setprio(0);
    // spill pmx + e (folded) to wave-private LDS [cluster32][pt32] f32
#pragma unroll
    for (int mtc = 0; mtc < 2; ++mtc)
#pragma unroll
      for (int nt = 0; nt < 2; ++nt)
#pragma unroll
        for (int r = 0; r < 4; ++r)
          pmxw[(mtc * 16 + q * 4 + r) * 32 + nt * 16 + l4] = pmx[mtc][nt][r] + ev[mtc][r];

    f32x4 accY[4][2];
#pragma unroll
    for (int mt = 0; mt < 4; ++mt)
#pragma unroll
      for (int nt = 0; nt < 2; ++nt) accY[mt][nt] = Z4;
    float lsum0 = 0.f, lsum1 = 0.f;

    // ---- k-loop: register-double-buffered P, no barriers ----
#pragma unroll 2
    for (int k = 0; k < KC; ++k) {
      const int cur = k & 1, nxt = cur ^ 1;
      const int kn = (k + 1) & (KC - 1);  // wraps to 0 on last step (harmless)
#pragma unroll
      for (int mt = 0; mt < 4; ++mt)
#pragma unroll
        for (int s = 0; s < 2; ++s)
          ap[nxt][mt][s] = PswF[kn * 512 + (mt * 2 + s) * 64 + lane];

      // y = P x, s-outer emission: 8 independent s=0 MFMAs, then 8 s=1 MFMAs.
      // setprio(1) keeps the matrix pipe fed while sibling waves run chains.
      f32x4 y[4][2];
      __builtin_amdgcn_s_setprio(1);
#pragma unroll
      for (int mt = 0; mt < 4; ++mt)
#pragma unroll
        for (int nt = 0; nt < 2; ++nt)
          y[mt][nt] = __builtin_amdgcn_mfma_f32_16x16x32_bf16(ap[cur][mt][0], bx[0][nt], Z4, 0, 0, 0);
#pragma unroll
      for (int mt = 0; mt < 4; ++mt)
#pragma unroll
        for (int nt = 0; nt < 2; ++nt)
          y[mt][nt] =
              __builtin_amdgcn_mfma_f32_16x16x32_bf16(ap[cur][mt][1], bx[1][nt], y[mt][nt], 0, 0, 0);
      __builtin_amdgcn_s_setprio(0);

      // xy[pt] = x . y : packed fp32 FMAs, chain depth 4
      f32x4 d0 = xm[0][0] * y[0][0];
      f32x4 d1 = xm[0][1] * y[0][1];
#pragma unroll
      for (int mt = 1; mt < 4; ++mt) {
        d0 += xm[mt][0] * y[mt][0];
        d1 += xm[mt][1] * y[mt][1];
      }
      float xy0 = (d0[0] + d0[1]) + (d0[2] + d0[3]);
      float xy1 = (d1[0] + d1[1]) + (d1[2] + d1[3]);
      xy0 = red32(red16(xy0));
      xy1 = red32(red16(xy1));

      const float pk0 = pmxw[k * 32 + l4];       // includes e_k
      const float pk1 = pmxw[k * 32 + 16 + l4];
      const float w0 = __expf(pk0 - 0.5f * xy0);
      const float w1 = __expf(pk1 - 0.5f * xy1);
      lsum0 += w0;
      lsum1 += w1;
      if (q == 0) {
        wtw[l4 * WT_PITCH + k] = __float2bfloat16(w0);
        wtw[(16 + l4) * WT_PITCH + k] = __float2bfloat16(w1);
      }
      // accY += w * y (packed fp32 FMA)
#pragma unroll
      for (int mt = 0; mt < 4; ++mt) {
        accY[mt][0] += w0 * y[mt][0];
        accY[mt][1] += w1 * y[mt][1];
      }
    }

    // ---- pacc[dim][pt] = sum_k Pmu[k][dim] * wt[k][pt]  (one K=32 GEMM) ----
    bf16x8 wtf[2];
#pragma unroll
    for (int nt = 0; nt < 2; ++nt)
      wtf[nt] = *(const bf16x8*)&wtw[(nt * 16 + l4) * WT_PITCH + q * 8];
    f32x4 pacc[4][2];
    __builtin_amdgcn_s_setprio(1);
#pragma unroll
    for (int mt = 0; mt < 4; ++mt) {
      bf16x8 a = PmuBF[mt * 64 + lane];
      pacc[mt][0] = __builtin_amdgcn_mfma_f32_16x16x32_bf16(a, wtf[0], Z4, 0, 0, 0);
      pacc[mt][1] = __builtin_amdgcn_mfma_f32_16x16x32_bf16(a, wtf[1], Z4, 0, 0, 0);
    }
    __builtin_amdgcn_s_setprio(0);

    // ---- x += (alpha/l) * (pacc - accY) ----
    const float c0 = alpha / lsum0;
    const float c1 = alpha / lsum1;
#pragma unroll
    for (int mt = 0; mt < 4; ++mt) {
      xm[mt][0] += c0 * (pacc[mt][0] - accY[mt][0]);
      xm[mt][1] += c1 * (pacc[mt][1] - accY[mt][1]);
    }
  }  // iterations

  // ---- direct f32x4 stores: 64B-contiguous per quad-row, fully in-bounds ---
#pragma unroll
  for (int mt = 0; mt < 4; ++mt)
#pragma unroll
    for (int nt = 0; nt < 2; ++nt)
      *(f32x4*)&out[(base_pt + nt * 16 + l4) * 64 + mt * 16 + q * 4] = xm[mt][nt];
}

extern "C" void kernel_launch(void* const* d_in, const int* in_sizes, int n_in,
                              void* d_out, int out_size, void* d_ws, size_t ws_size,
                              hipStream_t stream) {
  (void)in_sizes; (void)n_in; (void)out_size; (void)ws_size;
  const float* x = (const float*)d_in[0];
  const float* c = (const float*)d_in[1];
  const float* mu = (const float*)d_in[2];
  const float* A = (const float*)d_in[3];
  const float* alpha = (const float*)d_in[4];
  float* out = (float*)d_out;

  char* ws = (char*)d_ws;
  float* Pmu_g = (float*)(ws);                           // 8192 B
  float* e_g = (float*)(ws + 8192);                      // 128 B (pad to 256)
  __hip_bfloat16* Psw = (__hip_bfloat16*)(ws + 16640);   // 262144 B

  precompute1<<<32, 256, 0, stream>>>(A, mu, c, Pmu_g, e_g, Psw);
  denoise_main<<<512, 256, 0, stream>>>(x, e_g, alpha, Psw, Pmu_g, out);
}

// Round 12
// 278.769 us; speedup vs baseline: 1.4152x; 1.0293x over previous
//
#include <hip/hip_runtime.h>
#include <hip/hip_bf16.h>

// DenoisingPotential: x_{t+1} = x_t + alpha * grad_phi(x_t), 10 iters.
// grad = (pacc - sum_k w_k y_k)/l,  y_k = P_k x,  w_k = exp(e_k + Pmu_k.x - 0.5 x.y_k)
//
// R15: (a) revert R14's s_setprio (main 233->238 regression, matches m190's
// GEMM-negative result: at 2 blk/CU it preempts the sibling chains that ARE
// the critical path). (b) The ~48us tail is precompute1 (32 blocks = 12.5%
// chip). Split each k into 4 column-strips -> 128 blocks; per block: stage A,
// compute 64x16 strip of P=A^T A, write its Psw quarter, Pmu for its 16 dims
// (wave0 + shuffle reduce). e needs cross-strip data -> each block writes
// partial ep[k][strip] = sum_strip mu*Pmu; denoise prologue computes
// e = c - 0.5*sum(ep). precompute2 stays eliminated (Pmu frags staged to LDS
// in denoise prologue, one barrier before the iter loop).

typedef __attribute__((ext_vector_type(4))) float f32x4;
typedef __attribute__((ext_vector_type(8))) short bf16x8;  // 8 bf16 = 4 VGPRs

#define KC 32
#define NITER 10
#define XROW 72        // bf16 elems per point-row in xs staging (pad vs 64)
#define WT_PITCH 40    // bf16 pitch of weight stash (pad vs 32)
#define PW_BYTES 7168  // per-wave: xsw(4608, aliased by pmxw 4096) + wtw(2560)
// LDS total (main): 4*7168 + 2*4096 (PmuA/PmuB bf16) = 36864 B

static __device__ __forceinline__ unsigned pk_bf16(float a, float b) {
  __hip_bfloat16 ha = __float2bfloat16(a), hb = __float2bfloat16(b);
  unsigned short ua = *(unsigned short*)&ha, ub = *(unsigned short*)&hb;
  return (unsigned)ua | ((unsigned)ub << 16);
}

// butterfly sum with lane^16: permlane16_swap is pure VALU (sum of the two
// outputs = x[l] + x[l^16] in every lane)
static __device__ __forceinline__ float red16(float x) {
#if __has_builtin(__builtin_amdgcn_permlane16_swap)
  int xi = __float_as_int(x);
  auto pr = __builtin_amdgcn_permlane16_swap(xi, xi, false, false);
  return __int_as_float(pr[0]) + __int_as_float(pr[1]);
#else
  int v = __builtin_amdgcn_ds_swizzle(__float_as_int(x), 0x401F);
  return x + __int_as_float(v);
#endif
}
// butterfly sum with lane^32 (VALU permlane32_swap)
static __device__ __forceinline__ float red32(float x) {
  int xi = __float_as_int(x);
  auto pr = __builtin_amdgcn_permlane32_swap(xi, xi, false, false);
  return __int_as_float(pr[0]) + __int_as_float(pr[1]);
}

// ---------------- precompute 1 (split): per (k, strip) ----------------------
// 128 blocks: k = blockIdx.x>>2, strip st = blockIdx.x&3 (cols st*16..+16).
// Computes P[:, strip] in f32, writes Psw frags (st,0),(st,1), Pmu for its
// 16 dims, and the e-partial ep[k*4+st] = sum_{i in strip} mu[i]*Pmu[i].
__global__ void precompute1(const float* __restrict__ A, const float* __restrict__ mu,
                            float* __restrict__ Pmu_g, float* __restrict__ ep_g,
                            __hip_bfloat16* __restrict__ Psw) {
  __shared__ float As[64 * 64];   // 16 KB
  __shared__ float Ps[64 * 16];   // P rows x strip cols, 4 KB
  __shared__ float Pmu_s[16];
  const int k = blockIdx.x >> 2, st = blockIdx.x & 3, tid = threadIdx.x;
  const float* Ak = A + k * 4096;
  for (int idx = tid; idx < 1024; idx += 256)
    *(f32x4*)&As[idx * 4] = *(const f32x4*)&Ak[idx * 4];
  __syncthreads();

  // thread -> row i = tid>>2 (64 rows), cols st*16 + lg*4 .. +4
  const int i = tid >> 2, lg = tid & 3;
  f32x4 acc = {0.f, 0.f, 0.f, 0.f};
  for (int j = 0; j < 64; ++j) {
    float ai = As[j * 64 + i];                                    // broadcast
    f32x4 v = *(const f32x4*)&As[j * 64 + st * 16 + lg * 4];      // broadcast
    acc += ai * v;  // P[i][st*16+lg*4+r]
  }
  *(f32x4*)&Ps[i * 16 + lg * 4] = acc;
  __syncthreads();

  // Pmu[st*16+c] = sum_l P[l][st*16+c] * mu[l]  (wave 0: lane = lh*16 + c)
  if (tid < 64) {
    const int c = tid & 15, lh = tid >> 4;
    float s = 0.f;
#pragma unroll
    for (int ll = 0; ll < 16; ++ll) s += Ps[(lh * 16 + ll) * 16 + c] * mu[k * 64 + lh * 16 + ll];
    s += __shfl_xor(s, 16, 64);
    s += __shfl_xor(s, 32, 64);
    if (lh == 0) {
      Pmu_s[c] = s;
      Pmu_g[k * 64 + st * 16 + c] = s;
    }
  }
  __syncthreads();
  if (tid == 0) {
    float v = 0.f;
#pragma unroll
    for (int c2 = 0; c2 < 16; ++c2) v += mu[k * 64 + st * 16 + c2] * Pmu_s[c2];
    ep_g[k * 4 + st] = v;  // partial of mu^T P mu
  }

  // Psw frags for this strip: global u32 index = st*512 + idx2, idx2 in [0,512)
  // flat_local = idx2*2 = s*512 + ln*8 + j (j even); val pair =
  // P[rb][st*16+l4], P[rb+1][...] with rb = s*32 + qq*8 + j.
  unsigned* Psw32 = (unsigned*)(Psw + k * 4096);
  for (int idx2 = tid; idx2 < 512; idx2 += 256) {
    int fl = idx2 << 1;
    int s = fl >> 9, ln = (fl >> 3) & 63, j = fl & 7;
    int qq = ln >> 4, l4 = ln & 15;
    int rb = s * 32 + qq * 8 + j;
    Psw32[st * 512 + idx2] = pk_bf16(Ps[rb * 16 + l4], Ps[(rb + 1) * 16 + l4]);
  }
}

// ---------------- main kernel ----------------------------------------------
// 256 thr (4 waves), 32 pts/wave, grid 512. k-loop barrier-free; all per-wave
// LDS is wave-private. P via register double-buffer from L2. Pmu fragments
// staged into block LDS once in the prologue (one barrier, before iter loop).
__launch_bounds__(256, 2)
__global__ void denoise_main(const float* __restrict__ x_in,
                             const float* __restrict__ c_g,
                             const float* __restrict__ ep_g,
                             const float* __restrict__ alpha_g,
                             const __hip_bfloat16* __restrict__ Psw,
                             const float* __restrict__ Pmu_g,
                             float* __restrict__ out) {
  __shared__ __attribute__((aligned(16))) char scratch[4 * PW_BYTES];  // 28 KB
  __shared__ __attribute__((aligned(16))) __hip_bfloat16 pmuA_s[2048];  // 4 KB
  __shared__ __attribute__((aligned(16))) __hip_bfloat16 pmuB_s[2048];  // 4 KB

  const int tid = threadIdx.x;
  const int wave = tid >> 6, lane = tid & 63;
  const int q = lane >> 4, l4 = lane & 15;
  const int base_pt = blockIdx.x * 128 + wave * 32;
  const float alpha = alpha_g[0];

  char* pw = scratch + wave * PW_BYTES;
  __hip_bfloat16* xsw = (__hip_bfloat16*)pw;           // [32][XROW] bf16 staging
  float* pmxw = (float*)pw;                            // [32][32] f32 (xsw dead)
  __hip_bfloat16* wtw = (__hip_bfloat16*)(pw + 4608);  // [32][WT_PITCH] bf16

  const bf16x8* PswF = (const bf16x8*)Psw;  // frag idx = k*512 + f*64 + lane

  // ---- prologue: stage PmuA/PmuB fragment layouts into LDS (from Pmu_g) ----
  // PmuA (pmx GEMM A-operand): A[m=cluster][kk=dim]; frag f=(mtc,s)
  for (int idx = tid; idx < 2048; idx += 256) {
    int f = idx >> 9, ln = (idx >> 3) & 63, j = idx & 7;
    int mtc = f >> 1, s = f & 1, qq = ln >> 4, l4i = ln & 15;
    pmuA_s[idx] = __float2bfloat16(Pmu_g[(mtc * 16 + l4i) * 64 + s * 32 + qq * 8 + j]);
  }
  // PmuB (pacc GEMM A-operand): A[m=dim][kk=cluster]; frag f=mtd (K=32, 1 step)
  for (int idx = tid; idx < 2048; idx += 256) {
    int f = idx >> 9, ln = (idx >> 3) & 63, j = idx & 7;
    int qq = ln >> 4, l4i = ln & 15;
    pmuB_s[idx] = __float2bfloat16(Pmu_g[(qq * 8 + j) * 64 + f * 16 + l4i]);
  }

  // x master, C-layout: xm[mt][nt][r] = x[dim = mt*16+q*4+r][pt = nt*16+l4]
  f32x4 xm[4][2];
#pragma unroll
  for (int mt = 0; mt < 4; ++mt)
#pragma unroll
    for (int nt = 0; nt < 2; ++nt)
      xm[mt][nt] = *(const f32x4*)&x_in[(base_pt + nt * 16 + l4) * 64 + mt * 16 + q * 4];

  // e[cl] = c[cl] - 0.5 * sum_strips ep[cl*4+st]; ev[mtc][r] for cl=mtc*16+q*4+r
  f32x4 ev[2];
#pragma unroll
  for (int mtc = 0; mtc < 2; ++mtc)
#pragma unroll
    for (int r = 0; r < 4; ++r) {
      const int cl = mtc * 16 + q * 4 + r;
      const f32x4 ep = *(const f32x4*)&ep_g[cl * 4];
      ev[mtc][r] = c_g[cl] - 0.5f * ((ep[0] + ep[1]) + (ep[2] + ep[3]));
    }

  const f32x4 Z4 = {0.f, 0.f, 0.f, 0.f};
  const bf16x8* PmuAF = (const bf16x8*)pmuA_s;  // frag idx = f*64 + lane
  const bf16x8* PmuBF = (const bf16x8*)pmuB_s;

  __syncthreads();  // Pmu fragments staged; k-loop below stays barrier-free

#pragma unroll 1
  for (int it = 0; it < NITER; ++it) {
    // ---- stage x (bf16) into wave-private rows [pt][dim], XROW-padded ----
#pragma unroll
    for (int mt = 0; mt < 4; ++mt)
#pragma unroll
      for (int nt = 0; nt < 2; ++nt) {
        uint2 v;
        v.x = pk_bf16(xm[mt][nt][0], xm[mt][nt][1]);
        v.y = pk_bf16(xm[mt][nt][2], xm[mt][nt][3]);
        *(uint2*)&xsw[(nt * 16 + l4) * XROW + mt * 16 + q * 4] = v;
      }

    // ---- B-frags of x: B[kk=dim=s*32+q*8+j][n=pt=l4] (constant over k) ----
    bf16x8 bx[2][2];
#pragma unroll
    for (int s = 0; s < 2; ++s)
#pragma unroll
      for (int nt = 0; nt < 2; ++nt)
        bx[s][nt] = *(const bf16x8*)&xsw[(nt * 16 + l4) * XROW + s * 32 + q * 8];

    // ---- preload P(k=0) fragments into register buffer 0 ----
    bf16x8 ap[2][4][2];
#pragma unroll
    for (int mt = 0; mt < 4; ++mt)
#pragma unroll
      for (int s = 0; s < 2; ++s)
        ap[0][mt][s] = PswF[(mt * 2 + s) * 64 + lane];

    // ---- pmx GEMM (s-outer; Pmu frags from LDS) ----
    f32x4 pmx[2][2];
#pragma unroll
    for (int mtc = 0; mtc < 2; ++mtc)
#pragma unroll
      for (int nt = 0; nt < 2; ++nt)
        pmx[mtc][nt] =
            __builtin_amdgcn_mfma_f32_16x16x32_bf16(PmuAF[(mtc * 2) * 64 + lane], bx[0][nt], Z4, 0, 0, 0);
#pragma unroll
    for (int mtc = 0; mtc < 2; ++mtc)
#pragma unroll
      for (int nt = 0; nt < 2; ++nt)
        pmx[mtc][nt] = __builtin_amdgcn_mfma_f32_16x16x32_bf16(PmuAF[(mtc * 2 + 1) * 64 + lane],
                                                               bx[1][nt], pmx[mtc][nt], 0, 0, 0);
    // spill pmx + e (folded) to wave-private LDS [cluster32][pt32] f32
#pragma unroll
    for (int mtc = 0; mtc < 2; ++mtc)
#pragma unroll
      for (int nt = 0; nt < 2; ++nt)
#pragma unroll
        for (int r = 0; r < 4; ++r)
          pmxw[(mtc * 16 + q * 4 + r) * 32 + nt * 16 + l4] = pmx[mtc][nt][r] + ev[mtc][r];

    f32x4 accY[4][2];
#pragma unroll
    for (int mt = 0; mt < 4; ++mt)
#pragma unroll
      for (int nt = 0; nt < 2; ++nt) accY[mt][nt] = Z4;
    float lsum0 = 0.f, lsum1 = 0.f;

    // ---- k-loop: register-double-buffered P, no barriers ----
#pragma unroll 2
    for (int k = 0; k < KC; ++k) {
      const int cur = k & 1, nxt = cur ^ 1;
      const int kn = (k + 1) & (KC - 1);  // wraps to 0 on last step (harmless)
#pragma unroll
      for (int mt = 0; mt < 4; ++mt)
#pragma unroll
        for (int s = 0; s < 2; ++s)
          ap[nxt][mt][s] = PswF[kn * 512 + (mt * 2 + s) * 64 + lane];

      // y = P x, s-outer emission: 8 independent s=0 MFMAs, then 8 s=1 MFMAs
      f32x4 y[4][2];
#pragma unroll
      for (int mt = 0; mt < 4; ++mt)
#pragma unroll
        for (int nt = 0; nt < 2; ++nt)
          y[mt][nt] = __builtin_amdgcn_mfma_f32_16x16x32_bf16(ap[cur][mt][0], bx[0][nt], Z4, 0, 0, 0);
#pragma unroll
      for (int mt = 0; mt < 4; ++mt)
#pragma unroll
        for (int nt = 0; nt < 2; ++nt)
          y[mt][nt] =
              __builtin_amdgcn_mfma_f32_16x16x32_bf16(ap[cur][mt][1], bx[1][nt], y[mt][nt], 0, 0, 0);

      // xy[pt] = x . y : packed fp32 FMAs, chain depth 4
      f32x4 d0 = xm[0][0] * y[0][0];
      f32x4 d1 = xm[0][1] * y[0][1];
#pragma unroll
      for (int mt = 1; mt < 4; ++mt) {
        d0 += xm[mt][0] * y[mt][0];
        d1 += xm[mt][1] * y[mt][1];
      }
      float xy0 = (d0[0] + d0[1]) + (d0[2] + d0[3]);
      float xy1 = (d1[0] + d1[1]) + (d1[2] + d1[3]);
      xy0 = red32(red16(xy0));
      xy1 = red32(red16(xy1));

      const float pk0 = pmxw[k * 32 + l4];       // includes e_k
      const float pk1 = pmxw[k * 32 + 16 + l4];
      const float w0 = __expf(pk0 - 0.5f * xy0);
      const float w1 = __expf(pk1 - 0.5f * xy1);
      lsum0 += w0;
      lsum1 += w1;
      if (q == 0) {
        wtw[l4 * WT_PITCH + k] = __float2bfloat16(w0);
        wtw[(16 + l4) * WT_PITCH + k] = __float2bfloat16(w1);
      }
      // accY += w * y (packed fp32 FMA)
#pragma unroll
      for (int mt = 0; mt < 4; ++mt) {
        accY[mt][0] += w0 * y[mt][0];
        accY[mt][1] += w1 * y[mt][1];
      }
    }

    // ---- pacc[dim][pt] = sum_k Pmu[k][dim] * wt[k][pt]  (one K=32 GEMM) ----
    bf16x8 wtf[2];
#pragma unroll
    for (int nt = 0; nt < 2; ++nt)
      wtf[nt] = *(const bf16x8*)&wtw[(nt * 16 + l4) * WT_PITCH + q * 8];
    f32x4 pacc[4][2];
#pragma unroll
    for (int mt = 0; mt < 4; ++mt) {
      bf16x8 a = PmuBF[mt * 64 + lane];
      pacc[mt][0] = __builtin_amdgcn_mfma_f32_16x16x32_bf16(a, wtf[0], Z4, 0, 0, 0);
      pacc[mt][1] = __builtin_amdgcn_mfma_f32_16x16x32_bf16(a, wtf[1], Z4, 0, 0, 0);
    }

    // ---- x += (alpha/l) * (pacc - accY) ----
    const float c0 = alpha / lsum0;
    const float c1 = alpha / lsum1;
#pragma unroll
    for (int mt = 0; mt < 4; ++mt) {
      xm[mt][0] += c0 * (pacc[mt][0] - accY[mt][0]);
      xm[mt][1] += c1 * (pacc[mt][1] - accY[mt][1]);
    }
  }  // iterations

  // ---- direct f32x4 stores: 64B-contiguous per quad-row, fully in-bounds ---
#pragma unroll
  for (int mt = 0; mt < 4; ++mt)
#pragma unroll
    for (int nt = 0; nt < 2; ++nt)
      *(f32x4*)&out[(base_pt + nt * 16 + l4) * 64 + mt * 16 + q * 4] = xm[mt][nt];
}

extern "C" void kernel_launch(void* const* d_in, const int* in_sizes, int n_in,
                              void* d_out, int out_size, void* d_ws, size_t ws_size,
                              hipStream_t stream) {
  (void)in_sizes; (void)n_in; (void)out_size; (void)ws_size;
  const float* x = (const float*)d_in[0];
  const float* c = (const float*)d_in[1];
  const float* mu = (const float*)d_in[2];
  const float* A = (const float*)d_in[3];
  const float* alpha = (const float*)d_in[4];
  float* out = (float*)d_out;

  char* ws = (char*)d_ws;
  float* Pmu_g = (float*)(ws);                           // 8192 B
  float* ep_g = (float*)(ws + 8192);                     // 512 B (32 k x 4 strips)
  __hip_bfloat16* Psw = (__hip_bfloat16*)(ws + 16640);   // 262144 B

  precompute1<<<128, 256, 0, stream>>>(A, mu, Pmu_g, ep_g, Psw);
  denoise_main<<<512, 256, 0, stream>>>(x, c, ep_g, alpha, Psw, Pmu_g, out);
}

// Round 13
// 262.152 us; speedup vs baseline: 1.5049x; 1.0634x over previous
//
#include <hip/hip_runtime.h>
#include <hip/hip_bf16.h>

// DenoisingPotential: x_{t+1} = x_t + alpha * grad_phi(x_t), 10 iters.
// grad = (pacc - sum_k w_k y_k)/l,  y_k = P_k x,  w_k = exp(e_k + Pmu_k.x - 0.5 x.y_k)
//
// R16: port the k-loop to 32x32x16 MFMA (2382 vs 2075 TF ubench). Halves the
// serial path: 8 MFMA issues/k (was 16); C-layout col=lane&31 -> each lane
// owns ONE point -> 1 exp (was 2), 1 pmxw read, reduce = single permlane32
// (was red16+red32). pmx GEMM 4 MFMAs (was 8), pacc 4 (was 8). precompute1
// stays 128-block parallel and now also scatter-writes PmuA/PmuB fragments
// (each (k,strip) block owns exactly the 16 Pmu values those need). e folded
// via a 32-float wave-LDS table. k-loop keeps R9's register double-buffer +
// interleaved mt0/mt1 emission. A/B operand layout: row=lane&31,
// k=(lane>>5)*8+j; C: row=(reg&3)+8*(reg>>2)+4*(lane>>5) [m74/m101].

typedef __attribute__((ext_vector_type(4))) float f32x4;
typedef __attribute__((ext_vector_type(16))) float f32x16;
typedef __attribute__((ext_vector_type(8))) short bf16x8;  // 8 bf16 = 4 VGPRs

#define KC 32
#define NITER 10
#define XROW 72        // bf16 elems per point-row in xs staging (pad vs 64)
#define WT_PITCH 40    // bf16 pitch of weight stash (pad vs 32)
#define PW_BYTES 7296  // xsw(4608, aliased by pmxw 4096) + wtw(2560) + ew(128)
// LDS total (main): 4 * 7296 = 29184 B

static __device__ __forceinline__ unsigned pk_bf16(float a, float b) {
  __hip_bfloat16 ha = __float2bfloat16(a), hb = __float2bfloat16(b);
  unsigned short ua = *(unsigned short*)&ha, ub = *(unsigned short*)&hb;
  return (unsigned)ua | ((unsigned)ub << 16);
}

// butterfly sum with lane^32 (VALU permlane32_swap; sum of the two outputs =
// x[l] + x[l^32] in every lane)
static __device__ __forceinline__ float red32(float x) {
  int xi = __float_as_int(x);
  auto pr = __builtin_amdgcn_permlane32_swap(xi, xi, false, false);
  return __int_as_float(pr[0]) + __int_as_float(pr[1]);
}

// ---------------- precompute 1 (parallel): per (k, strip) -------------------
// 128 blocks: k = blockIdx.x>>2, strip st = blockIdx.x&3 (in-dims st*16..+16).
// Computes P[:, strip], writes Psw frags f = mt*4+st (32x32x16 A-layout),
// Pmu for its 16 dims -> scatter into PmuA/PmuB fragment buffers, and the
// e-partial ep[k*4+st] = sum_{d in strip} mu[d]*Pmu[d].
__global__ void precompute1(const float* __restrict__ A, const float* __restrict__ mu,
                            float* __restrict__ ep_g,
                            __hip_bfloat16* __restrict__ PmuA,
                            __hip_bfloat16* __restrict__ PmuB,
                            __hip_bfloat16* __restrict__ Psw) {
  __shared__ float As[64 * 64];  // 16 KB
  __shared__ float Ps[64 * 16];  // P rows x strip cols, 4 KB
  __shared__ float Pmu_s[16];
  const int k = blockIdx.x >> 2, st = blockIdx.x & 3, tid = threadIdx.x;
  const float* Ak = A + k * 4096;
  for (int idx = tid; idx < 1024; idx += 256)
    *(f32x4*)&As[idx * 4] = *(const f32x4*)&Ak[idx * 4];
  __syncthreads();

  // thread -> row i = tid>>2 (64 rows), strip cols lg*4..+4
  const int i = tid >> 2, lg = tid & 3;
  f32x4 acc = {0.f, 0.f, 0.f, 0.f};
  for (int j = 0; j < 64; ++j) {
    float ai = As[j * 64 + i];                                // broadcast
    f32x4 v = *(const f32x4*)&As[j * 64 + st * 16 + lg * 4];  // broadcast
    acc += ai * v;  // P[i][st*16 + lg*4 + r]
  }
  *(f32x4*)&Ps[i * 16 + lg * 4] = acc;
  __syncthreads();

  // Pmu[st*16+c] = sum_l P[l][st*16+c] * mu[l]  (wave 0)
  if (tid < 64) {
    const int c = tid & 15, lh = tid >> 4;
    float s = 0.f;
#pragma unroll
    for (int ll = 0; ll < 16; ++ll) s += Ps[(lh * 16 + ll) * 16 + c] * mu[k * 64 + lh * 16 + ll];
    s += __shfl_xor(s, 16, 64);
    s += __shfl_xor(s, 32, 64);
    if (lh == 0) Pmu_s[c] = s;
  }
  __syncthreads();

  if (tid == 0) {
    float v = 0.f;
#pragma unroll
    for (int c2 = 0; c2 < 16; ++c2) v += mu[k * 64 + st * 16 + c2] * Pmu_s[c2];
    ep_g[k * 4 + st] = v;  // partial of mu^T P mu
  }

  // scatter this (k,strip)'s 16 Pmu values into the fragment buffers:
  // PmuA (pmx A-op): value(f=c, lane l, j) = Pmu[cluster=l&31][dim=c*16+(l>>5)*8+j]
  // PmuB (pacc A-op): value(f=mt*2+c, l, j) = Pmu[cl=c*16+(l>>5)*8+j][dim=mt*32+(l&31)]
  if (tid < 16) {
    const int dl = tid;  // dim local; global dim = st*16 + dl
    __hip_bfloat16 pv = __float2bfloat16(Pmu_s[dl]);
    PmuA[st * 512 + (dl >> 3) * 256 + k * 8 + (dl & 7)] = pv;
    PmuB[((st >> 1) * 2 + (k >> 4)) * 512 + (((k >> 3) & 1) * 32 + (st & 1) * 16 + dl) * 8 +
         (k & 7)] = pv;
  }

  // Psw frags f = mt*4 + st: value(l, j) = P[mt*32 + (l&31)][st*16 + (l>>5)*8 + j]
  unsigned* Psw32 = (unsigned*)(Psw + k * 4096);
  for (int idx2 = tid; idx2 < 512; idx2 += 256) {
    int mt = idx2 >> 8, rem = idx2 & 255;
    int l = rem >> 2, jj = rem & 3;
    int row = mt * 32 + (l & 31), cl = (l >> 5) * 8 + 2 * jj;
    Psw32[(mt * 4 + st) * 256 + rem] = pk_bf16(Ps[row * 16 + cl], Ps[row * 16 + cl + 1]);
  }
}

// ---------------- main kernel ----------------------------------------------
// 256 thr (4 waves), 32 pts/wave (one pt per lane, 2-way h-redundant),
// grid 512. Barrier-free; wave-private LDS. P via register double-buffer.
__launch_bounds__(256, 2)
__global__ void denoise_main(const float* __restrict__ x_in,
                             const float* __restrict__ c_g,
                             const float* __restrict__ ep_g,
                             const float* __restrict__ alpha_g,
                             const __hip_bfloat16* __restrict__ Psw,
                             const __hip_bfloat16* __restrict__ PmuA,
                             const __hip_bfloat16* __restrict__ PmuB,
                             float* __restrict__ out) {
  __shared__ __attribute__((aligned(16))) char scratch[4 * PW_BYTES];  // 28.5 KB

  const int tid = threadIdx.x;
  const int wave = tid >> 6, lane = tid & 63;
  const int pt = lane & 31, h = lane >> 5;
  const int base_pt = blockIdx.x * 128 + wave * 32;
  const float alpha = alpha_g[0];

  char* pw = scratch + wave * PW_BYTES;
  __hip_bfloat16* xsw = (__hip_bfloat16*)pw;           // [32][XROW] bf16 staging
  float* pmxw = (float*)pw;                            // [32 cl][32 pt] f32 (xsw dead)
  __hip_bfloat16* wtw = (__hip_bfloat16*)(pw + 4608);  // [32 pt][WT_PITCH] bf16
  float* eww = (float*)(pw + 7168);                    // [32] e per cluster

  const bf16x8* PswF = (const bf16x8*)Psw;    // frag idx = k*512 + f*64 + lane
  const bf16x8* PmuAF = (const bf16x8*)PmuA;  // frag idx = c*64 + lane
  const bf16x8* PmuBF = (const bf16x8*)PmuB;  // frag idx = f*64 + lane

  // e[cl] = c[cl] - 0.5*sum_st ep[cl*4+st]  -> wave-private LDS table
  if (lane < 32) {
    const f32x4 ep = *(const f32x4*)&ep_g[lane * 4];
    eww[lane] = c_g[lane] - 0.5f * ((ep[0] + ep[1]) + (ep[2] + ep[3]));
  }

  // x master in 32x32 C-layout: xm[t][rq][rr] = x[dim = t*32+8*rq+4*h+rr][pt]
  f32x4 xm[2][4];
#pragma unroll
  for (int t = 0; t < 2; ++t)
#pragma unroll
    for (int rq = 0; rq < 4; ++rq)
      xm[t][rq] = *(const f32x4*)&x_in[(base_pt + pt) * 64 + t * 32 + 8 * rq + 4 * h];

  const f32x16 Z16 = {0.f, 0.f, 0.f, 0.f, 0.f, 0.f, 0.f, 0.f,
                      0.f, 0.f, 0.f, 0.f, 0.f, 0.f, 0.f, 0.f};

#pragma unroll 1
  for (int it = 0; it < NITER; ++it) {
    // ---- stage x (bf16) into wave-private rows [pt][dim], XROW-padded ----
#pragma unroll
    for (int t = 0; t < 2; ++t)
#pragma unroll
      for (int rq = 0; rq < 4; ++rq) {
        uint2 v;
        v.x = pk_bf16(xm[t][rq][0], xm[t][rq][1]);
        v.y = pk_bf16(xm[t][rq][2], xm[t][rq][3]);
        *(uint2*)&xsw[pt * XROW + t * 32 + 8 * rq + 4 * h] = v;
      }

    // ---- B-frags of x: B[k=c*16+h*8+j][n=pt] (constant over k-loop) ----
    bf16x8 bx[4];
#pragma unroll
    for (int c = 0; c < 4; ++c)
      bx[c] = *(const bf16x8*)&xsw[pt * XROW + c * 16 + h * 8];

    // ---- preload P(k=0) fragments into register buffer 0 ----
    bf16x8 ap[2][8];
#pragma unroll
    for (int f = 0; f < 8; ++f) ap[0][f] = PswF[f * 64 + lane];

    // ---- pmx GEMM: pmx[cluster][pt], one 32x32 tile, 4 chained MFMAs ----
    f32x16 pmx = Z16;
#pragma unroll
    for (int c = 0; c < 4; ++c)
      pmx = __builtin_amdgcn_mfma_f32_32x32x16_bf16(PmuAF[c * 64 + lane], bx[c], pmx, 0, 0, 0);
    // spill pmx + e (from LDS table) to wave-private pmxw[cluster][pt]
#pragma unroll
    for (int r = 0; r < 16; ++r) {
      const int cl = (r & 3) + 8 * (r >> 2) + 4 * h;
      pmxw[cl * 32 + pt] = pmx[r] + eww[cl];
    }

    f32x16 accY0 = Z16, accY1 = Z16;
    float lsum = 0.f;

    // ---- k-loop: register-double-buffered P, no barriers ----
#pragma unroll 2
    for (int k = 0; k < KC; ++k) {
      const int cur = k & 1, nxt = cur ^ 1;
      const int kn = (k + 1) & (KC - 1);  // wraps to 0 on last step (harmless)
#pragma unroll
      for (int f = 0; f < 8; ++f) ap[nxt][f] = PswF[kn * 512 + f * 64 + lane];

      // y = P x : two 32-row tiles, interleaved emission (dep gap = 2 issues)
      f32x16 y0, y1;
      y0 = __builtin_amdgcn_mfma_f32_32x32x16_bf16(ap[cur][0], bx[0], Z16, 0, 0, 0);
      y1 = __builtin_amdgcn_mfma_f32_32x32x16_bf16(ap[cur][4], bx[0], Z16, 0, 0, 0);
      y0 = __builtin_amdgcn_mfma_f32_32x32x16_bf16(ap[cur][1], bx[1], y0, 0, 0, 0);
      y1 = __builtin_amdgcn_mfma_f32_32x32x16_bf16(ap[cur][5], bx[1], y1, 0, 0, 0);
      y0 = __builtin_amdgcn_mfma_f32_32x32x16_bf16(ap[cur][2], bx[2], y0, 0, 0, 0);
      y1 = __builtin_amdgcn_mfma_f32_32x32x16_bf16(ap[cur][6], bx[2], y1, 0, 0, 0);
      y0 = __builtin_amdgcn_mfma_f32_32x32x16_bf16(ap[cur][3], bx[3], y0, 0, 0, 0);
      y1 = __builtin_amdgcn_mfma_f32_32x32x16_bf16(ap[cur][7], bx[3], y1, 0, 0, 0);

      // xy[pt] = x . y : 32 own dims + partner half via ONE permlane32
      f32x4 d = {0.f, 0.f, 0.f, 0.f};
#pragma unroll
      for (int rq = 0; rq < 4; ++rq) {
        f32x4 yq0 = {y0[4 * rq], y0[4 * rq + 1], y0[4 * rq + 2], y0[4 * rq + 3]};
        f32x4 yq1 = {y1[4 * rq], y1[4 * rq + 1], y1[4 * rq + 2], y1[4 * rq + 3]};
        d += xm[0][rq] * yq0;
        d += xm[1][rq] * yq1;
      }
      const float xy = red32((d[0] + d[1]) + (d[2] + d[3]));

      const float pk = pmxw[k * 32 + pt];  // includes e_k
      const float w = __expf(pk - 0.5f * xy);
      lsum += w;
      if (lane < 32) wtw[pt * WT_PITCH + k] = __float2bfloat16(w);
      accY0 += y0 * w;
      accY1 += y1 * w;
    }

    // ---- pacc[dim][pt] = sum_cl Pmu[cl][dim] * wt[cl][pt] (4 MFMAs) ----
    bf16x8 wtf0 = *(const bf16x8*)&wtw[pt * WT_PITCH + h * 8];
    bf16x8 wtf1 = *(const bf16x8*)&wtw[pt * WT_PITCH + 16 + h * 8];
    f32x16 pacc0, pacc1;
    pacc0 = __builtin_amdgcn_mfma_f32_32x32x16_bf16(PmuBF[0 * 64 + lane], wtf0, Z16, 0, 0, 0);
    pacc1 = __builtin_amdgcn_mfma_f32_32x32x16_bf16(PmuBF[2 * 64 + lane], wtf0, Z16, 0, 0, 0);
    pacc0 = __builtin_amdgcn_mfma_f32_32x32x16_bf16(PmuBF[1 * 64 + lane], wtf1, pacc0, 0, 0, 0);
    pacc1 = __builtin_amdgcn_mfma_f32_32x32x16_bf16(PmuBF[3 * 64 + lane], wtf1, pacc1, 0, 0, 0);

    // ---- x += (alpha/l) * (pacc - accY) ----
    const float cc = alpha / lsum;
#pragma unroll
    for (int rq = 0; rq < 4; ++rq) {
      f32x4 p0 = {pacc0[4 * rq], pacc0[4 * rq + 1], pacc0[4 * rq + 2], pacc0[4 * rq + 3]};
      f32x4 a0 = {accY0[4 * rq], accY0[4 * rq + 1], accY0[4 * rq + 2], accY0[4 * rq + 3]};
      xm[0][rq] += cc * (p0 - a0);
      f32x4 p1 = {pacc1[4 * rq], pacc1[4 * rq + 1], pacc1[4 * rq + 2], pacc1[4 * rq + 3]};
      f32x4 a1 = {accY1[4 * rq], accY1[4 * rq + 1], accY1[4 * rq + 2], accY1[4 * rq + 3]};
      xm[1][rq] += cc * (p1 - a1);
    }
  }  // iterations

  // ---- f32x4 stores (16B per lane; lane pair covers 32B of each row) ----
#pragma unroll
  for (int t = 0; t < 2; ++t)
#pragma unroll
    for (int rq = 0; rq < 4; ++rq)
      *(f32x4*)&out[(base_pt + pt) * 64 + t * 32 + 8 * rq + 4 * h] = xm[t][rq];
}

extern "C" void kernel_launch(void* const* d_in, const int* in_sizes, int n_in,
                              void* d_out, int out_size, void* d_ws, size_t ws_size,
                              hipStream_t stream) {
  (void)in_sizes; (void)n_in; (void)out_size; (void)ws_size;
  const float* x = (const float*)d_in[0];
  const float* c = (const float*)d_in[1];
  const float* mu = (const float*)d_in[2];
  const float* A = (const float*)d_in[3];
  const float* alpha = (const float*)d_in[4];
  float* out = (float*)d_out;

  char* ws = (char*)d_ws;
  float* ep_g = (float*)ws;                             // 512 B (32 k x 4 strips)
  __hip_bfloat16* PmuA = (__hip_bfloat16*)(ws + 1024);  // 4096 B
  __hip_bfloat16* PmuB = (__hip_bfloat16*)(ws + 5120);  // 4096 B
  __hip_bfloat16* Psw = (__hip_bfloat16*)(ws + 9216);   // 262144 B

  precompute1<<<128, 256, 0, stream>>>(A, mu, ep_g, PmuA, PmuB, Psw);
  denoise_main<<<512, 256, 0, stream>>>(x, c, ep_g, alpha, Psw, PmuA, PmuB, out);
}

// Round 14
// 255.366 us; speedup vs baseline: 1.5449x; 1.0266x over previous
//
#include <hip/hip_runtime.h>
#include <hip/hip_bf16.h>

// DenoisingPotential: x_{t+1} = x_t + alpha * grad_phi(x_t), 10 iters.
// grad = (pacc - sum_k w_k y_k)/l,  y_k = P_k x,  w_k = exp(e_k + Pmu_k.x - 0.5 x.y_k)
//
// R17: R16 (32x32x16 port, main 233->222) still spills ~13MB (FETCH 15.9 vs
// clean 9.3, WRITE 29.7 vs 16.4): live set xm32+accY32+y32+apDBUF64+bx16=186
// vs the 128-VGPR pin. The ap double-buffer is obsolete: distance-2 prefetch
// covered ~200cy L2 latency, but one k-step wall-time at 2 blk/CU is ~700cy,
// so loads issued AFTER step k's MFMA block land well before k+1. R17:
// single ap[8] (32 regs) -- MFMAs consume ap, then 8 loads refill the same
// regs for k+1 (old frags dead -> no rename pressure), chain runs under the
// loads. Compiler-tracked vmcnt. Everything else identical to R16.

typedef __attribute__((ext_vector_type(4))) float f32x4;
typedef __attribute__((ext_vector_type(16))) float f32x16;
typedef __attribute__((ext_vector_type(8))) short bf16x8;  // 8 bf16 = 4 VGPRs

#define KC 32
#define NITER 10
#define XROW 72        // bf16 elems per point-row in xs staging (pad vs 64)
#define WT_PITCH 40    // bf16 pitch of weight stash (pad vs 32)
#define PW_BYTES 7296  // xsw(4608, aliased by pmxw 4096) + wtw(2560) + ew(128)
// LDS total (main): 4 * 7296 = 29184 B

static __device__ __forceinline__ unsigned pk_bf16(float a, float b) {
  __hip_bfloat16 ha = __float2bfloat16(a), hb = __float2bfloat16(b);
  unsigned short ua = *(unsigned short*)&ha, ub = *(unsigned short*)&hb;
  return (unsigned)ua | ((unsigned)ub << 16);
}

// butterfly sum with lane^32 (VALU permlane32_swap; sum of the two outputs =
// x[l] + x[l^32] in every lane)
static __device__ __forceinline__ float red32(float x) {
  int xi = __float_as_int(x);
  auto pr = __builtin_amdgcn_permlane32_swap(xi, xi, false, false);
  return __int_as_float(pr[0]) + __int_as_float(pr[1]);
}

// ---------------- precompute 1 (parallel): per (k, strip) -------------------
// 128 blocks: k = blockIdx.x>>2, strip st = blockIdx.x&3 (in-dims st*16..+16).
// Computes P[:, strip], writes Psw frags f = mt*4+st (32x32x16 A-layout),
// Pmu for its 16 dims -> scatter into PmuA/PmuB fragment buffers, and the
// e-partial ep[k*4+st] = sum_{d in strip} mu[d]*Pmu[d].
__global__ void precompute1(const float* __restrict__ A, const float* __restrict__ mu,
                            float* __restrict__ ep_g,
                            __hip_bfloat16* __restrict__ PmuA,
                            __hip_bfloat16* __restrict__ PmuB,
                            __hip_bfloat16* __restrict__ Psw) {
  __shared__ float As[64 * 64];  // 16 KB
  __shared__ float Ps[64 * 16];  // P rows x strip cols, 4 KB
  __shared__ float Pmu_s[16];
  const int k = blockIdx.x >> 2, st = blockIdx.x & 3, tid = threadIdx.x;
  const float* Ak = A + k * 4096;
  for (int idx = tid; idx < 1024; idx += 256)
    *(f32x4*)&As[idx * 4] = *(const f32x4*)&Ak[idx * 4];
  __syncthreads();

  // thread -> row i = tid>>2 (64 rows), strip cols lg*4..+4
  const int i = tid >> 2, lg = tid & 3;
  f32x4 acc = {0.f, 0.f, 0.f, 0.f};
  for (int j = 0; j < 64; ++j) {
    float ai = As[j * 64 + i];                                // broadcast
    f32x4 v = *(const f32x4*)&As[j * 64 + st * 16 + lg * 4];  // broadcast
    acc += ai * v;  // P[i][st*16 + lg*4 + r]
  }
  *(f32x4*)&Ps[i * 16 + lg * 4] = acc;
  __syncthreads();

  // Pmu[st*16+c] = sum_l P[l][st*16+c] * mu[l]  (wave 0)
  if (tid < 64) {
    const int c = tid & 15, lh = tid >> 4;
    float s = 0.f;
#pragma unroll
    for (int ll = 0; ll < 16; ++ll) s += Ps[(lh * 16 + ll) * 16 + c] * mu[k * 64 + lh * 16 + ll];
    s += __shfl_xor(s, 16, 64);
    s += __shfl_xor(s, 32, 64);
    if (lh == 0) Pmu_s[c] = s;
  }
  __syncthreads();

  if (tid == 0) {
    float v = 0.f;
#pragma unroll
    for (int c2 = 0; c2 < 16; ++c2) v += mu[k * 64 + st * 16 + c2] * Pmu_s[c2];
    ep_g[k * 4 + st] = v;  // partial of mu^T P mu
  }

  // scatter this (k,strip)'s 16 Pmu values into the fragment buffers:
  // PmuA (pmx A-op): value(f=c, lane l, j) = Pmu[cluster=l&31][dim=c*16+(l>>5)*8+j]
  // PmuB (pacc A-op): value(f=mt*2+c, l, j) = Pmu[cl=c*16+(l>>5)*8+j][dim=mt*32+(l&31)]
  if (tid < 16) {
    const int dl = tid;  // dim local; global dim = st*16 + dl
    __hip_bfloat16 pv = __float2bfloat16(Pmu_s[dl]);
    PmuA[st * 512 + (dl >> 3) * 256 + k * 8 + (dl & 7)] = pv;
    PmuB[((st >> 1) * 2 + (k >> 4)) * 512 + (((k >> 3) & 1) * 32 + (st & 1) * 16 + dl) * 8 +
         (k & 7)] = pv;
  }

  // Psw frags f = mt*4 + st: value(l, j) = P[mt*32 + (l&31)][st*16 + (l>>5)*8 + j]
  unsigned* Psw32 = (unsigned*)(Psw + k * 4096);
  for (int idx2 = tid; idx2 < 512; idx2 += 256) {
    int mt = idx2 >> 8, rem = idx2 & 255;
    int l = rem >> 2, jj = rem & 3;
    int row = mt * 32 + (l & 31), cl = (l >> 5) * 8 + 2 * jj;
    Psw32[(mt * 4 + st) * 256 + rem] = pk_bf16(Ps[row * 16 + cl], Ps[row * 16 + cl + 1]);
  }
}

// ---------------- main kernel ----------------------------------------------
// 256 thr (4 waves), 32 pts/wave (one pt per lane, 2-way h-redundant),
// grid 512. Barrier-free; wave-private LDS. P via SINGLE register buffer:
// refill issued right after the MFMA block, lands during the softmax chain.
__launch_bounds__(256, 2)
__global__ void denoise_main(const float* __restrict__ x_in,
                             const float* __restrict__ c_g,
                             const float* __restrict__ ep_g,
                             const float* __restrict__ alpha_g,
                             const __hip_bfloat16* __restrict__ Psw,
                             const __hip_bfloat16* __restrict__ PmuA,
                             const __hip_bfloat16* __restrict__ PmuB,
                             float* __restrict__ out) {
  __shared__ __attribute__((aligned(16))) char scratch[4 * PW_BYTES];  // 28.5 KB

  const int tid = threadIdx.x;
  const int wave = tid >> 6, lane = tid & 63;
  const int pt = lane & 31, h = lane >> 5;
  const int base_pt = blockIdx.x * 128 + wave * 32;
  const float alpha = alpha_g[0];

  char* pw = scratch + wave * PW_BYTES;
  __hip_bfloat16* xsw = (__hip_bfloat16*)pw;           // [32][XROW] bf16 staging
  float* pmxw = (float*)pw;                            // [32 cl][32 pt] f32 (xsw dead)
  __hip_bfloat16* wtw = (__hip_bfloat16*)(pw + 4608);  // [32 pt][WT_PITCH] bf16
  float* eww = (float*)(pw + 7168);                    // [32] e per cluster

  const bf16x8* PswF = (const bf16x8*)Psw;    // frag idx = k*512 + f*64 + lane
  const bf16x8* PmuAF = (const bf16x8*)PmuA;  // frag idx = c*64 + lane
  const bf16x8* PmuBF = (const bf16x8*)PmuB;  // frag idx = f*64 + lane

  // e[cl] = c[cl] - 0.5*sum_st ep[cl*4+st]  -> wave-private LDS table
  if (lane < 32) {
    const f32x4 ep = *(const f32x4*)&ep_g[lane * 4];
    eww[lane] = c_g[lane] - 0.5f * ((ep[0] + ep[1]) + (ep[2] + ep[3]));
  }

  // x master in 32x32 C-layout: xm[t][rq][rr] = x[dim = t*32+8*rq+4*h+rr][pt]
  f32x4 xm[2][4];
#pragma unroll
  for (int t = 0; t < 2; ++t)
#pragma unroll
    for (int rq = 0; rq < 4; ++rq)
      xm[t][rq] = *(const f32x4*)&x_in[(base_pt + pt) * 64 + t * 32 + 8 * rq + 4 * h];

  const f32x16 Z16 = {0.f, 0.f, 0.f, 0.f, 0.f, 0.f, 0.f, 0.f,
                      0.f, 0.f, 0.f, 0.f, 0.f, 0.f, 0.f, 0.f};

  // single P-fragment buffer; preloaded once, refilled each k-step (and the
  // k=31 step wraps to k=0, pre-loading the next iteration's first step)
  bf16x8 ap[8];
#pragma unroll
  for (int f = 0; f < 8; ++f) ap[f] = PswF[f * 64 + lane];

#pragma unroll 1
  for (int it = 0; it < NITER; ++it) {
    // ---- stage x (bf16) into wave-private rows [pt][dim], XROW-padded ----
#pragma unroll
    for (int t = 0; t < 2; ++t)
#pragma unroll
      for (int rq = 0; rq < 4; ++rq) {
        uint2 v;
        v.x = pk_bf16(xm[t][rq][0], xm[t][rq][1]);
        v.y = pk_bf16(xm[t][rq][2], xm[t][rq][3]);
        *(uint2*)&xsw[pt * XROW + t * 32 + 8 * rq + 4 * h] = v;
      }

    // ---- B-frags of x: B[k=c*16+h*8+j][n=pt] (constant over k-loop) ----
    bf16x8 bx[4];
#pragma unroll
    for (int c = 0; c < 4; ++c)
      bx[c] = *(const bf16x8*)&xsw[pt * XROW + c * 16 + h * 8];

    // ---- pmx GEMM: pmx[cluster][pt], one 32x32 tile, 4 chained MFMAs ----
    f32x16 pmx = Z16;
#pragma unroll
    for (int c = 0; c < 4; ++c)
      pmx = __builtin_amdgcn_mfma_f32_32x32x16_bf16(PmuAF[c * 64 + lane], bx[c], pmx, 0, 0, 0);
    // spill pmx + e (from LDS table) to wave-private pmxw[cluster][pt]
#pragma unroll
    for (int r = 0; r < 16; ++r) {
      const int cl = (r & 3) + 8 * (r >> 2) + 4 * h;
      pmxw[cl * 32 + pt] = pmx[r] + eww[cl];
    }

    f32x16 accY0 = Z16, accY1 = Z16;
    float lsum = 0.f;

    // ---- k-loop: single-buffered P, refill under the chain, no barriers ---
#pragma unroll 2
    for (int k = 0; k < KC; ++k) {
      const int kn = (k + 1) & (KC - 1);  // k=31 wraps: preloads next iter k=0
      const bf16x8* PswN = PswF + kn * 512;

      // y = P x : two 32-row tiles, interleaved emission (dep gap = 2 issues)
      f32x16 y0, y1;
      y0 = __builtin_amdgcn_mfma_f32_32x32x16_bf16(ap[0], bx[0], Z16, 0, 0, 0);
      y1 = __builtin_amdgcn_mfma_f32_32x32x16_bf16(ap[4], bx[0], Z16, 0, 0, 0);
      y0 = __builtin_amdgcn_mfma_f32_32x32x16_bf16(ap[1], bx[1], y0, 0, 0, 0);
      y1 = __builtin_amdgcn_mfma_f32_32x32x16_bf16(ap[5], bx[1], y1, 0, 0, 0);
      y0 = __builtin_amdgcn_mfma_f32_32x32x16_bf16(ap[2], bx[2], y0, 0, 0, 0);
      y1 = __builtin_amdgcn_mfma_f32_32x32x16_bf16(ap[6], bx[2], y1, 0, 0, 0);
      y0 = __builtin_amdgcn_mfma_f32_32x32x16_bf16(ap[3], bx[3], y0, 0, 0, 0);
      y1 = __builtin_amdgcn_mfma_f32_32x32x16_bf16(ap[7], bx[3], y1, 0, 0, 0);

      // refill ap for k+1 (all frags dead now; loads land during the chain)
#pragma unroll
      for (int f = 0; f < 8; ++f) ap[f] = PswN[f * 64 + lane];

      // xy[pt] = x . y : 32 own dims + partner half via ONE permlane32
      f32x4 d = {0.f, 0.f, 0.f, 0.f};
#pragma unroll
      for (int rq = 0; rq < 4; ++rq) {
        f32x4 yq0 = {y0[4 * rq], y0[4 * rq + 1], y0[4 * rq + 2], y0[4 * rq + 3]};
        f32x4 yq1 = {y1[4 * rq], y1[4 * rq + 1], y1[4 * rq + 2], y1[4 * rq + 3]};
        d += xm[0][rq] * yq0;
        d += xm[1][rq] * yq1;
      }
      const float xy = red32((d[0] + d[1]) + (d[2] + d[3]));

      const float pk = pmxw[k * 32 + pt];  // includes e_k
      const float w = __expf(pk - 0.5f * xy);
      lsum += w;
      if (lane < 32) wtw[pt * WT_PITCH + k] = __float2bfloat16(w);
      accY0 += y0 * w;
      accY1 += y1 * w;
    }

    // ---- pacc[dim][pt] = sum_cl Pmu[cl][dim] * wt[cl][pt] (4 MFMAs) ----
    bf16x8 wtf0 = *(const bf16x8*)&wtw[pt * WT_PITCH + h * 8];
    bf16x8 wtf1 = *(const bf16x8*)&wtw[pt * WT_PITCH + 16 + h * 8];
    f32x16 pacc0, pacc1;
    pacc0 = __builtin_amdgcn_mfma_f32_32x32x16_bf16(PmuBF[0 * 64 + lane], wtf0, Z16, 0, 0, 0);
    pacc1 = __builtin_amdgcn_mfma_f32_32x32x16_bf16(PmuBF[2 * 64 + lane], wtf0, Z16, 0, 0, 0);
    pacc0 = __builtin_amdgcn_mfma_f32_32x32x16_bf16(PmuBF[1 * 64 + lane], wtf1, pacc0, 0, 0, 0);
    pacc1 = __builtin_amdgcn_mfma_f32_32x32x16_bf16(PmuBF[3 * 64 + lane], wtf1, pacc1, 0, 0, 0);

    // ---- x += (alpha/l) * (pacc - accY) ----
    const float cc = alpha / lsum;
#pragma unroll
    for (int rq = 0; rq < 4; ++rq) {
      f32x4 p0 = {pacc0[4 * rq], pacc0[4 * rq + 1], pacc0[4 * rq + 2], pacc0[4 * rq + 3]};
      f32x4 a0 = {accY0[4 * rq], accY0[4 * rq + 1], accY0[4 * rq + 2], accY0[4 * rq + 3]};
      xm[0][rq] += cc * (p0 - a0);
      f32x4 p1 = {pacc1[4 * rq], pacc1[4 * rq + 1], pacc1[4 * rq + 2], pacc1[4 * rq + 3]};
      f32x4 a1 = {accY1[4 * rq], accY1[4 * rq + 1], accY1[4 * rq + 2], accY1[4 * rq + 3]};
      xm[1][rq] += cc * (p1 - a1);
    }
  }  // iterations

  // ---- f32x4 stores (16B per lane; lane pair covers 32B of each row) ----
#pragma unroll
  for (int t = 0; t < 2; ++t)
#pragma unroll
    for (int rq = 0; rq < 4; ++rq)
      *(f32x4*)&out[(base_pt + pt) * 64 + t * 32 + 8 * rq + 4 * h] = xm[t][rq];
}

extern "C" void kernel_launch(void* const* d_in, const int* in_sizes, int n_in,
                              void* d_out, int out_size, void* d_ws, size_t ws_size,
                              hipStream_t stream) {
  (void)in_sizes; (void)n_in; (void)out_size; (void)ws_size;
  const float* x = (const float*)d_in[0];
  const float* c = (const float*)d_in[1];
  const float* mu = (const float*)d_in[2];
  const float* A = (const float*)d_in[3];
  const float* alpha = (const float*)d_in[4];
  float* out = (float*)d_out;

  char* ws = (char*)d_ws;
  float* ep_g = (float*)ws;                             // 512 B (32 k x 4 strips)
  __hip_bfloat16* PmuA = (__hip_bfloat16*)(ws + 1024);  // 4096 B
  __hip_bfloat16* PmuB = (__hip_bfloat16*)(ws + 5120);  // 4096 B
  __hip_bfloat16* Psw = (__hip_bfloat16*)(ws + 9216);   // 262144 B

  precompute1<<<128, 256, 0, stream>>>(A, mu, ep_g, PmuA, PmuB, Psw);
  denoise_main<<<512, 256, 0, stream>>>(x, c, ep_g, alpha, Psw, PmuA, PmuB, out);
}